// Round 4
// baseline (210.632 us; speedup 1.0000x reference)
//
#include <hip/hip_runtime.h>

// ImportanceAggregator pipeline:
//   K0 convert_w    : W[k][c] fp32 -> wtp, bf16 packed in MFMA B-frag order
//   K1 convert_feat : feat fp32 -> featb bf16 (halves pool gather bytes)
//   K2 pool_b       : agg[n] = sum_k w~[n,k] * featb[nbr[n,k]]; 2 nodes/wave,
//                     32 lanes x ushort8 per row (fp32 acc, bf16 out)
//   K3 gemm_ln      : out = LN(agg @ W + b)*gamma + beta via MFMA 16x16x32.
//                     2 m-tiles/wave (B-frag reused 2x), NO LDS, NO barriers,
//                     direct 64B-segment stores. 8 latency-independent waves/CU.
// agg bf16 rows live in d_out at 1 KB stride; every block reads only its own
// rows then overwrites exactly those rows (dataflow-ordered) -> no hazard.

#define NN   50000
#define KNB  16
#define D    256

typedef __attribute__((ext_vector_type(8))) short short8;   // 8 x bf16 (4 VGPRs)
typedef __attribute__((ext_vector_type(4))) float f32x4;

static __device__ __forceinline__ unsigned short f2bf(float x) {
    unsigned int u = __float_as_uint(x);
    return (unsigned short)((u + 0x7FFFu + ((u >> 16) & 1u)) >> 16);  // RNE
}
static __device__ __forceinline__ float bf2f(unsigned short h) {
    return __uint_as_float((unsigned int)h << 16);
}

// ---------------- K0: W -> bf16 packed in B-fragment order ----------------
// frag g = (c*8 + kb32)*64 + lane holds B[k = quad*8 + kb32*32 + j][n = c*16 + l15]
__global__ __launch_bounds__(256) void convert_w(const float* __restrict__ Wm,
                                                 unsigned short* __restrict__ wtp) {
    const int g    = blockIdx.x * 256 + threadIdx.x;   // 0..8191
    const int lane = g & 63;
    const int kb32 = (g >> 6) & 7;
    const int c    = g >> 9;
    const int n    = c * 16 + (lane & 15);
    const int k0   = kb32 * 32 + (lane >> 4) * 8;
    short8 v;
    #pragma unroll
    for (int j = 0; j < 8; ++j) v[j] = (short)f2bf(Wm[(size_t)(k0 + j) * D + n]);
    *(short8*)(wtp + (size_t)g * 8) = v;               // 16 B/thread, coalesced
}

// ---------------- K1: features fp32 -> bf16 -------------------------------
__global__ __launch_bounds__(256) void convert_feat(const float* __restrict__ feat,
                                                    unsigned short* __restrict__ featb) {
    const size_t g = (size_t)blockIdx.x * 256 + threadIdx.x;  // 1.6M threads, 8 elem each
    const float4 a = *(const float4*)(feat + g * 8);
    const float4 b = *(const float4*)(feat + g * 8 + 4);
    short8 o;
    o[0] = (short)f2bf(a.x); o[1] = (short)f2bf(a.y);
    o[2] = (short)f2bf(a.z); o[3] = (short)f2bf(a.w);
    o[4] = (short)f2bf(b.x); o[5] = (short)f2bf(b.y);
    o[6] = (short)f2bf(b.z); o[7] = (short)f2bf(b.w);
    *(short8*)(featb + g * 8) = o;
}

// ---------------- K2: weighted neighbor pooling (2 nodes per wave) --------
__global__ __launch_bounds__(256, 6) void pool_b(const unsigned short* __restrict__ featb,
                                                 const int*   __restrict__ nbr,
                                                 const float* __restrict__ iw,
                                                 unsigned short* __restrict__ aggb) {
    const int  t   = threadIdx.x;
    const int  l31 = t & 31;
    const long n   = (long)blockIdx.x * 8 + (t >> 5);   // half-wave per node

    float w[KNB];
    int   idx[KNB];
    #pragma unroll
    for (int q = 0; q < 4; ++q) {                       // 64 B row each, half-broadcast
        const float4 w4 = *(const float4*)(iw  + n * KNB + q * 4);
        const int4   i4 = *(const int4*)  (nbr + n * KNB + q * 4);
        w[q*4+0] = w4.x; w[q*4+1] = w4.y; w[q*4+2] = w4.z; w[q*4+3] = w4.w;
        idx[q*4+0] = i4.x; idx[q*4+1] = i4.y; idx[q*4+2] = i4.z; idx[q*4+3] = i4.w;
    }
    float ws = 0.f;
    #pragma unroll
    for (int k = 0; k < KNB; ++k) ws += w[k];
    const bool  zs  = (ws == 0.f);
    const float inv = zs ? (1.f / KNB) : (1.f / ws);

    float p[8] = {0.f, 0.f, 0.f, 0.f, 0.f, 0.f, 0.f, 0.f};
    #pragma unroll 1
    for (int kb = 0; kb < KNB; kb += 8) {               // 8 gathers in flight / batch
        #pragma unroll
        for (int k = 0; k < 8; ++k) {
            const float  wk = zs ? inv : (w[kb + k] * inv);
            const short8 u  = *(const short8*)(featb + (size_t)idx[kb + k] * D + l31 * 8);
            #pragma unroll
            for (int e = 0; e < 8; ++e)
                p[e] += wk * bf2f((unsigned short)u[e]);
        }
    }
    short8 o;
    #pragma unroll
    for (int e = 0; e < 8; ++e) o[e] = (short)f2bf(p[e]);
    *(short8*)(aggb + (size_t)n * 512 + l31 * 8) = o;   // row n @ 1 KB stride
}

// Fallback (ws too small for featb): fp32 gathers, one node per wave.
__global__ __launch_bounds__(256, 8) void pool_f(const float* __restrict__ feat,
                                                 const int*   __restrict__ nbr,
                                                 const float* __restrict__ iw,
                                                 unsigned short* __restrict__ aggb) {
    const int  t    = threadIdx.x;
    const int  lane = t & 63;
    const int  wq   = t >> 6;
    const long n    = (long)blockIdx.x * 4 + wq;
    float ws = 0.f;
    #pragma unroll
    for (int k = 0; k < KNB; ++k) ws += iw[n * KNB + k];
    const bool  zs  = (ws == 0.f);
    const float inv = zs ? (1.f / KNB) : (1.f / ws);
    float4 p = make_float4(0.f, 0.f, 0.f, 0.f);
    #pragma unroll 1
    for (int kb = 0; kb < KNB; kb += 8) {
        int idx[8]; float w[8];
        #pragma unroll
        for (int k = 0; k < 8; ++k) { idx[k] = nbr[n*KNB+kb+k]; w[k] = iw[n*KNB+kb+k]; }
        #pragma unroll
        for (int k = 0; k < 8; ++k) {
            const float  wk = zs ? inv : (w[k] * inv);
            const float4 f  = *(const float4*)(feat + (size_t)idx[k] * D + lane * 4);
            p.x += wk*f.x; p.y += wk*f.y; p.z += wk*f.z; p.w += wk*f.w;
        }
    }
    ushort4 o;
    o.x = f2bf(p.x); o.y = f2bf(p.y); o.z = f2bf(p.z); o.w = f2bf(p.w);
    *(ushort4*)(aggb + (size_t)n * 512 + lane * 4) = o;
}

// ---------------- K3: bf16 MFMA GEMM + LayerNorm (no LDS, no barriers) ----
// Wave: 2 m-tiles (32 rows) x 16 n-tiles; each B-frag load feeds 2 MFMAs.
__global__ __launch_bounds__(256, 2) void gemm_ln(const unsigned short* __restrict__ aggb,
                                                  const unsigned short* __restrict__ wtp,
                                                  const float* __restrict__ bias,
                                                  const float* __restrict__ gamma,
                                                  const float* __restrict__ beta,
                                                  float* __restrict__ out) {
    const int t       = threadIdx.x;
    const int lane    = t & 63;
    const int wq      = t >> 6;
    const int quad    = lane >> 4;
    const int l15     = lane & 15;
    const int rowbase = blockIdx.x * 128 + wq * 32;     // this wave: rows [rowbase, +32)

    const int ar0 = min(rowbase +      l15, NN - 1);
    const int ar1 = min(rowbase + 16 + l15, NN - 1);
    const unsigned short* ap0 = aggb + (size_t)ar0 * 512 + quad * 8;
    const unsigned short* ap1 = aggb + (size_t)ar1 * 512 + quad * 8;
    const short8* wv = (const short8*)wtp;

    f32x4 acc0[16], acc1[16];
    #pragma unroll
    for (int c = 0; c < 16; ++c) {
        acc0[c] = (f32x4){0.f, 0.f, 0.f, 0.f};
        acc1[c] = (f32x4){0.f, 0.f, 0.f, 0.f};
    }

    #pragma unroll
    for (int kb = 0; kb < 8; ++kb) {
        const short8 a0 = *(const short8*)(ap0 + kb * 32);
        const short8 a1 = *(const short8*)(ap1 + kb * 32);
        #pragma unroll
        for (int c = 0; c < 16; ++c) {
            const short8 b = wv[(size_t)(c * 8 + kb) * 64 + lane];  // dense 1 KB, L2-hot
            acc0[c] = __builtin_amdgcn_mfma_f32_16x16x32_bf16(a0, b, acc0[c], 0, 0, 0);
            acc1[c] = __builtin_amdgcn_mfma_f32_16x16x32_bf16(a1, b, acc1[c], 0, 0, 0);
        }
    }

    // Epilogue: +bias, LN over 256 cols, *gamma+beta, direct segment stores.
    float bv[16], gv[16], btv[16];
    #pragma unroll
    for (int c = 0; c < 16; ++c) {
        bv[c]  = bias [c * 16 + l15];
        gv[c]  = gamma[c * 16 + l15];
        btv[c] = beta [c * 16 + l15];
    }
    #pragma unroll
    for (int m = 0; m < 2; ++m) {
        const f32x4* acc = m ? acc1 : acc0;
        #pragma unroll
        for (int j = 0; j < 4; ++j) {       // C/D: row = quad*4 + j, col = c*16 + l15
            float s = 0.f, sq = 0.f;
            #pragma unroll
            for (int c = 0; c < 16; ++c) {
                const float v = acc[c][j] + bv[c];
                s += v; sq += v * v;
            }
            #pragma unroll
            for (int off = 1; off < 16; off <<= 1) {   // reduce across l15 (same quad)
                s  += __shfl_xor(s,  off, 64);
                sq += __shfl_xor(sq, off, 64);
            }
            const float mean = s * (1.f / D);
            const float var  = sq * (1.f / D) - mean * mean;   // biased (torch LN)
            const float rstd = rsqrtf(var + 1e-5f);
            const int   r    = rowbase + m * 16 + quad * 4 + j;
            if (r < NN) {
                float* op = out + (size_t)r * D + l15;
                #pragma unroll
                for (int c = 0; c < 16; ++c)           // 4x64B aligned segments/instr
                    op[c * 16] = (acc[c][j] + bv[c] - mean) * rstd * gv[c] + btv[c];
            }
        }
    }
}

extern "C" void kernel_launch(void* const* d_in, const int* in_sizes, int n_in,
                              void* d_out, int out_size, void* d_ws, size_t ws_size,
                              hipStream_t stream) {
    const float* feat = (const float*)d_in[0];
    const int*   nbr  = (const int*)d_in[1];
    const float* iw   = (const float*)d_in[2];
    const float* Wm   = (const float*)d_in[3];
    const float* b    = (const float*)d_in[4];
    const float* g    = (const float*)d_in[5];
    const float* be   = (const float*)d_in[6];
    float*       out  = (float*)d_out;

    unsigned short* wtp   = (unsigned short*)d_ws;                   // 128 KB
    unsigned short* featb = (unsigned short*)((char*)d_ws + 131072); // 25.6 MB
    unsigned short* aggb  = (unsigned short*)d_out;                  // bf16 rows @ 1 KB

    const size_t need = 131072 + (size_t)NN * D * 2;

    convert_w<<<dim3(32), dim3(256), 0, stream>>>(Wm, wtp);
    if (ws_size >= need) {
        convert_feat<<<dim3(6250),   dim3(256), 0, stream>>>(feat, featb);
        pool_b      <<<dim3(NN / 8), dim3(256), 0, stream>>>(featb, nbr, iw, aggb);
    } else {
        pool_f      <<<dim3(NN / 4), dim3(256), 0, stream>>>(feat, nbr, iw, aggb);
    }
    gemm_ln<<<dim3((NN + 127) / 128), dim3(256), 0, stream>>>(aggb, wtp, b, g, be, out);
}

// Round 5
// 204.662 us; speedup vs baseline: 1.0292x; 1.0292x over previous
//
#include <hip/hip_runtime.h>

// ImportanceAggregator pipeline:
//   K0 convert_w    : W[k][c] fp32 -> wtp, bf16 packed in MFMA B-frag order
//   K1 convert_feat : feat fp32 -> featb bf16 (halves pool gather bytes)
//   K2 pool_b       : agg[n] = sum_k w~[n,k] * featb[nbr[n,k]]; one wave/node
//                     (R3-proven form: local arrays INSIDE loop, const-indexed ->
//                      registers; R4's hoisted arrays got promoted to LDS = 3.6M
//                      bank conflicts + scratch traffic. Do not hoist.)
//   K3 gemm_ln      : out = LN(agg @ W + b)*gamma + beta via MFMA 16x16x32.
//                     1 m-tile/wave, NO LDS, NO barriers, direct 64B-segment
//                     stores, VGPR<=128 -> launch_bounds(256,4) = 16 waves/CU.
// agg bf16 rows live in d_out at 1 KB stride; every gemm_ln block reads only its
// own 64 rows then overwrites exactly those rows -> no cross-block hazard.

#define NN   50000
#define KNB  16
#define D    256

typedef __attribute__((ext_vector_type(8))) short short8;   // 8 x bf16 (4 VGPRs)
typedef __attribute__((ext_vector_type(4))) float f32x4;

static __device__ __forceinline__ unsigned short f2bf(float x) {
    unsigned int u = __float_as_uint(x);
    return (unsigned short)((u + 0x7FFFu + ((u >> 16) & 1u)) >> 16);  // RNE
}
static __device__ __forceinline__ float bf2f(unsigned short h) {
    return __uint_as_float((unsigned int)h << 16);
}

// ---------------- K0: W -> bf16 packed in B-fragment order ----------------
// frag g = (c*8 + kb32)*64 + lane holds B[k = quad*8 + kb32*32 + j][n = c*16 + l15]
__global__ __launch_bounds__(256) void convert_w(const float* __restrict__ Wm,
                                                 unsigned short* __restrict__ wtp) {
    const int g    = blockIdx.x * 256 + threadIdx.x;   // 0..8191
    const int lane = g & 63;
    const int kb32 = (g >> 6) & 7;
    const int c    = g >> 9;
    const int n    = c * 16 + (lane & 15);
    const int k0   = kb32 * 32 + (lane >> 4) * 8;
    short8 v;
    #pragma unroll
    for (int j = 0; j < 8; ++j) v[j] = (short)f2bf(Wm[(size_t)(k0 + j) * D + n]);
    *(short8*)(wtp + (size_t)g * 8) = v;               // 16 B/thread, coalesced
}

// ---------------- K1: features fp32 -> bf16 -------------------------------
__global__ __launch_bounds__(256) void convert_feat(const float* __restrict__ feat,
                                                    unsigned short* __restrict__ featb) {
    const size_t g = (size_t)blockIdx.x * 256 + threadIdx.x;  // 1.6M threads, 8 elem each
    const float4 a = *(const float4*)(feat + g * 8);
    const float4 b = *(const float4*)(feat + g * 8 + 4);
    short8 o;
    o[0] = (short)f2bf(a.x); o[1] = (short)f2bf(a.y);
    o[2] = (short)f2bf(a.z); o[3] = (short)f2bf(a.w);
    o[4] = (short)f2bf(b.x); o[5] = (short)f2bf(b.y);
    o[6] = (short)f2bf(b.z); o[7] = (short)f2bf(b.w);
    *(short8*)(featb + g * 8) = o;
}

// ---------------- K2: weighted neighbor pooling (bf16 gathers) ------------
// R3-proven form. NOTE: idx[]/w[] must stay inside the loop with constant
// indices only -> registers (hoisting triggers LDS promotion, see R4).
__global__ __launch_bounds__(256, 8) void pool_b(const unsigned short* __restrict__ featb,
                                                 const int*   __restrict__ nbr,
                                                 const float* __restrict__ iw,
                                                 unsigned short* __restrict__ aggb) {
    const int  t    = threadIdx.x;
    const int  lane = t & 63;
    const int  wq   = t >> 6;
    const long n    = (long)blockIdx.x * 4 + wq;   // one wave per node

    float ws = 0.f;
    #pragma unroll
    for (int k = 0; k < KNB; ++k) ws += iw[n * KNB + k];
    const bool  zs  = (ws == 0.f);
    const float inv = zs ? (1.f / KNB) : (1.f / ws);

    float4 p = make_float4(0.f, 0.f, 0.f, 0.f);
    #pragma unroll 1
    for (int kb = 0; kb < KNB; kb += 8) {          // 8 gathers in flight per batch
        int   idx[8];
        float w[8];
        #pragma unroll
        for (int k = 0; k < 8; ++k) {
            idx[k] = nbr[n * KNB + kb + k];
            w[k]   = iw [n * KNB + kb + k];
        }
        #pragma unroll
        for (int k = 0; k < 8; ++k) {
            const float   wk = zs ? inv : (w[k] * inv);
            const ushort4 u  = *(const ushort4*)(featb + (size_t)idx[k] * D + lane * 4);
            p.x += wk * bf2f(u.x); p.y += wk * bf2f(u.y);
            p.z += wk * bf2f(u.z); p.w += wk * bf2f(u.w);
        }
    }
    ushort4 o;
    o.x = f2bf(p.x); o.y = f2bf(p.y); o.z = f2bf(p.z); o.w = f2bf(p.w);
    *(ushort4*)(aggb + (size_t)n * 512 + lane * 4) = o;   // row n @ 1 KB stride
}

// Fallback (ws too small for featb): fp32 gathers, one node per wave.
__global__ __launch_bounds__(256, 8) void pool_f(const float* __restrict__ feat,
                                                 const int*   __restrict__ nbr,
                                                 const float* __restrict__ iw,
                                                 unsigned short* __restrict__ aggb) {
    const int  t    = threadIdx.x;
    const int  lane = t & 63;
    const int  wq   = t >> 6;
    const long n    = (long)blockIdx.x * 4 + wq;
    float ws = 0.f;
    #pragma unroll
    for (int k = 0; k < KNB; ++k) ws += iw[n * KNB + k];
    const bool  zs  = (ws == 0.f);
    const float inv = zs ? (1.f / KNB) : (1.f / ws);
    float4 p = make_float4(0.f, 0.f, 0.f, 0.f);
    #pragma unroll 1
    for (int kb = 0; kb < KNB; kb += 8) {
        int idx[8]; float w[8];
        #pragma unroll
        for (int k = 0; k < 8; ++k) { idx[k] = nbr[n*KNB+kb+k]; w[k] = iw[n*KNB+kb+k]; }
        #pragma unroll
        for (int k = 0; k < 8; ++k) {
            const float  wk = zs ? inv : (w[k] * inv);
            const float4 f  = *(const float4*)(feat + (size_t)idx[k] * D + lane * 4);
            p.x += wk*f.x; p.y += wk*f.y; p.z += wk*f.z; p.w += wk*f.w;
        }
    }
    ushort4 o;
    o.x = f2bf(p.x); o.y = f2bf(p.y); o.z = f2bf(p.z); o.w = f2bf(p.w);
    *(ushort4*)(aggb + (size_t)n * 512 + lane * 4) = o;
}

// ---------------- K3: bf16 MFMA GEMM + LayerNorm (no LDS, high occupancy) -
// Wave: 16 rows x 16 n-tiles, 128 MFMAs. acc = 64 VGPRs; total ~120 -> 4 waves/EU.
__global__ __launch_bounds__(256, 4) void gemm_ln(const unsigned short* __restrict__ aggb,
                                                  const unsigned short* __restrict__ wtp,
                                                  const float* __restrict__ bias,
                                                  const float* __restrict__ gamma,
                                                  const float* __restrict__ beta,
                                                  float* __restrict__ out) {
    const int t       = threadIdx.x;
    const int lane    = t & 63;
    const int wq      = t >> 6;
    const int quad    = lane >> 4;
    const int l15     = lane & 15;
    const int rowbase = blockIdx.x * 64 + wq * 16;

    const int arow = min(rowbase + l15, NN - 1);
    const unsigned short* aptr = aggb + (size_t)arow * 512 + quad * 8;
    const short8* wv = (const short8*)wtp;

    f32x4 acc[16];
    #pragma unroll
    for (int c = 0; c < 16; ++c) acc[c] = (f32x4){0.f, 0.f, 0.f, 0.f};

    #pragma unroll
    for (int kb = 0; kb < 8; ++kb) {
        const short8 a = *(const short8*)(aptr + kb * 32);
        #pragma unroll
        for (int c = 0; c < 16; ++c) {
            const short8 b = wv[(size_t)(c * 8 + kb) * 64 + lane];  // dense 1 KB, L2-hot
            acc[c] = __builtin_amdgcn_mfma_f32_16x16x32_bf16(a, b, acc[c], 0, 0, 0);
        }
    }

    // Epilogue: +bias, LN over 256 cols, *gamma+beta, direct segment stores.
    float bv[16];
    #pragma unroll
    for (int c = 0; c < 16; ++c) bv[c] = bias[c * 16 + l15];

    #pragma unroll
    for (int j = 0; j < 4; ++j) {       // C/D: row = quad*4 + j, col = c*16 + l15
        float s = 0.f, sq = 0.f;
        #pragma unroll
        for (int c = 0; c < 16; ++c) {
            const float v = acc[c][j] + bv[c];
            s += v; sq += v * v;
        }
        #pragma unroll
        for (int off = 1; off < 16; off <<= 1) {   // reduce across l15 (same quad)
            s  += __shfl_xor(s,  off, 64);
            sq += __shfl_xor(sq, off, 64);
        }
        const float mean = s * (1.f / D);
        const float var  = sq * (1.f / D) - mean * mean;   // biased (torch LN)
        const float rstd = rsqrtf(var + 1e-5f);
        const int   r    = rowbase + quad * 4 + j;
        if (r < NN) {
            float* op = out + (size_t)r * D + l15;
            #pragma unroll
            for (int c = 0; c < 16; ++c) {         // 4x64B aligned segments / instr
                const float v = acc[c][j] + bv[c];
                op[c * 16] = (v - mean) * rstd * gamma[c * 16 + l15] + beta[c * 16 + l15];
            }
        }
    }
}

extern "C" void kernel_launch(void* const* d_in, const int* in_sizes, int n_in,
                              void* d_out, int out_size, void* d_ws, size_t ws_size,
                              hipStream_t stream) {
    const float* feat = (const float*)d_in[0];
    const int*   nbr  = (const int*)d_in[1];
    const float* iw   = (const float*)d_in[2];
    const float* Wm   = (const float*)d_in[3];
    const float* b    = (const float*)d_in[4];
    const float* g    = (const float*)d_in[5];
    const float* be   = (const float*)d_in[6];
    float*       out  = (float*)d_out;

    unsigned short* wtp   = (unsigned short*)d_ws;                   // 128 KB
    unsigned short* featb = (unsigned short*)((char*)d_ws + 131072); // 25.6 MB
    unsigned short* aggb  = (unsigned short*)d_out;                  // bf16 rows @ 1 KB

    const size_t need = 131072 + (size_t)NN * D * 2;

    convert_w<<<dim3(32), dim3(256), 0, stream>>>(Wm, wtp);
    if (ws_size >= need) {
        convert_feat<<<dim3(6250),   dim3(256), 0, stream>>>(feat, featb);
        pool_b      <<<dim3(NN / 4), dim3(256), 0, stream>>>(featb, nbr, iw, aggb);
    } else {
        pool_f      <<<dim3(NN / 4), dim3(256), 0, stream>>>(feat, nbr, iw, aggb);
    }
    gemm_ln<<<dim3((NN + 63) / 64), dim3(256), 0, stream>>>(aggb, wtp, b, g, be, out);
}